// Round 1
// baseline (845.747 us; speedup 1.0000x reference)
//
#include <hip/hip_runtime.h>
#include <hip/hip_bf16.h>
#include <stdint.h>

// Problem constants (from reference)
#define KVOL   27
#define MPAIRS 150000
#define CDIM   64
#define N_IN_V 200000

typedef __attribute__((ext_vector_type(8))) short bf16x8;   // 8 bf16 = 4 VGPRs
typedef __attribute__((ext_vector_type(4))) float f32x4;

__device__ __forceinline__ short f2bf(float f) {
  union { float f; uint32_t u; } v; v.f = f;
  uint32_t u = v.u;
  u += 0x7FFF + ((u >> 16) & 1);   // round-to-nearest-even
  return (short)(u >> 16);
}

// ---- prologue: convert in_feats [N_IN][64] f32 -> bf16 ----
__global__ void cvt_feats(const float* __restrict__ in, short* __restrict__ out, int n8) {
  int i = blockIdx.x * blockDim.x + threadIdx.x;
  int stride = gridDim.x * blockDim.x;
  for (; i < n8; i += stride) {
    const float* p = in + (size_t)i * 8;
    f32x4 f0 = *(const f32x4*)(p);
    f32x4 f1 = *(const f32x4*)(p + 4);
    bf16x8 o;
    o[0] = f2bf(f0[0]); o[1] = f2bf(f0[1]); o[2] = f2bf(f0[2]); o[3] = f2bf(f0[3]);
    o[4] = f2bf(f1[0]); o[5] = f2bf(f1[1]); o[6] = f2bf(f1[2]); o[7] = f2bf(f1[3]);
    *(bf16x8*)(out + (size_t)i * 8) = o;
  }
}

// ---- prologue: W [27][64][64] f32 -> W^T bf16 as wt[k][j][i] ----
__global__ void cvt_w(const float* __restrict__ w, short* __restrict__ wt) {
  int k = blockIdx.x;
  const float* wk = w + (size_t)k * CDIM * CDIM;
  short* wtk = wt + (size_t)k * CDIM * CDIM;
  for (int t = threadIdx.x; t < CDIM * CDIM; t += blockDim.x) {
    int j = t >> 6;       // out channel
    int i = t & 63;       // in channel
    wtk[j * CDIM + i] = f2bf(wk[i * CDIM + j]);
  }
}

// ---- main: per offset k, tiles of 16 pairs; MFMA 16x16x32 bf16; atomic scatter ----
__global__ __launch_bounds__(256, 4)
void spconv_mfma(const short* __restrict__ a_bf16,   // [N_IN][64]
                 const short* __restrict__ wt_bf16,  // [27][64(out j)][64(in i)]
                 const int*   __restrict__ in_map,   // [27][M]
                 const int*   __restrict__ out_map,  // [27][M]
                 float*       __restrict__ out)      // [N_OUT][64]
{
  const int k    = blockIdx.y;
  const int lane = threadIdx.x & 63;
  const int wave = threadIdx.x >> 6;        // 0..3
  const int r    = lane & 15;               // A row / B col / D col selector
  const int h    = lane >> 4;               // 0..3

  // B fragments for this offset: b[t][c] covers cols t*16..t*16+15, K chunk c*32..c*32+31.
  // Fragment element: col j = t*16 + r, k = c*32 + h*8 + e  -> contiguous in wt[k][j][*].
  bf16x8 b[4][2];
  const short* wtk = wt_bf16 + (size_t)k * CDIM * CDIM;
#pragma unroll
  for (int t = 0; t < 4; ++t)
#pragma unroll
    for (int c = 0; c < 2; ++c)
      b[t][c] = *(const bf16x8*)(wtk + (t * 16 + r) * CDIM + c * 32 + h * 8);

  const int* imk = in_map  + (size_t)k * MPAIRS;
  const int* omk = out_map + (size_t)k * MPAIRS;
  const int ntiles = MPAIRS / 16;           // 9375, exact
  const int wstride = gridDim.x * 4;

  for (int tile = blockIdx.x * 4 + wave; tile < ntiles; tile += wstride) {
    const int base = tile * 16;
    // A fragment: row r of the 16-pair tile, k = c*32 + h*8 + e
    const int in_row = imk[base + r];
    const short* arow = a_bf16 + (size_t)in_row * CDIM;
    bf16x8 a0 = *(const bf16x8*)(arow + h * 8);
    bf16x8 a1 = *(const bf16x8*)(arow + 32 + h * 8);

    f32x4 acc[4];
#pragma unroll
    for (int t = 0; t < 4; ++t) {
      acc[t] = (f32x4){0.f, 0.f, 0.f, 0.f};
      acc[t] = __builtin_amdgcn_mfma_f32_16x16x32_bf16(a0, b[t][0], acc[t], 0, 0, 0);
      acc[t] = __builtin_amdgcn_mfma_f32_16x16x32_bf16(a1, b[t][1], acc[t], 0, 0, 0);
    }

    // D layout: col = r (lane&15), row = h*4 + rr. Scatter-add.
#pragma unroll
    for (int rr = 0; rr < 4; ++rr) {
      const int orow = omk[base + h * 4 + rr];
      float* orp = out + (size_t)orow * CDIM + r;
#pragma unroll
      for (int t = 0; t < 4; ++t)
        unsafeAtomicAdd(orp + t * 16, acc[t][rr]);
    }
  }
}

extern "C" void kernel_launch(void* const* d_in, const int* in_sizes, int n_in,
                              void* d_out, int out_size, void* d_ws, size_t ws_size,
                              hipStream_t stream) {
  const float* in_feats = (const float*)d_in[0];   // [200000][64]
  const float* kernel   = (const float*)d_in[1];   // [27][64][64]
  const int*   in_map   = (const int*)d_in[2];     // [27][150000]
  const int*   out_map  = (const int*)d_in[3];     // [27][150000]
  float* out = (float*)d_out;                      // [200000][64]

  const int n_in_rows = in_sizes[0] / CDIM;        // 200000

  // workspace layout: [in_bf16: n_in_rows*64 shorts][wt_bf16: 27*64*64 shorts]
  short* in_bf16 = (short*)d_ws;
  short* wt_bf16 = in_bf16 + (size_t)n_in_rows * CDIM;

  // zero output (harness poisons with 0xAA)
  hipMemsetAsync(d_out, 0, (size_t)out_size * sizeof(float), stream);

  // prologue conversions
  {
    int n8 = (in_sizes[0] + 7) / 8;                // 1.6M vec8 units
    cvt_feats<<<2048, 256, 0, stream>>>(in_feats, in_bf16, n8);
    cvt_w<<<KVOL, 256, 0, stream>>>(kernel, wt_bf16);
  }

  // main sparse-conv
  dim3 grid(96, KVOL);
  spconv_mfma<<<grid, 256, 0, stream>>>(in_bf16, wt_bf16, in_map, out_map, out);
}